// Round 2
// 844.515 us; speedup vs baseline: 1.0164x; 1.0164x over previous
//
#include <hip/hip_runtime.h>
#include <math.h>

// Problem constants (from reference)
#define N_NEURONS 4096
#define N_INPUTS  8192
#define K         4
#define ROW_FLOATS   (N_INPUTS * K)      // 32768 floats per neuron row
#define ROW_VEC4     (ROW_FLOATS / 4)    // 8192 float4 per row
#define BLOCK_T      512
#define N_WAVES      (BLOCK_T / 64)       // 8
#define VEC_PER_THR  (ROW_VEC4 / BLOCK_T) // 16 float4 per thread

#define DT_OVER_TAUV 0.05f   // DT / TAU_V = 0.01 / 0.2
#define ALPHA        0.5f
#define INV_TAU_W    0.02f   // 1 / 50

// Native vector type: accepted by __builtin_nontemporal_{load,store}
// (HIP's float4 is a struct and is rejected). Same 16B codegen.
typedef float v4f __attribute__((ext_vector_type(4)));

// __launch_bounds__(512, 4): 4 waves/EU = 16 waves/CU = 2 blocks/CU resident.
// Caps VGPR at 128 (wv[16] needs 64 + ~35 overhead -> fits, no spill), and
// guarantees two independent barrier groups per CU so one block streams HBM
// while the other sits in its reduce/barrier phase.
__global__ __launch_bounds__(BLOCK_T, 4) void dv_bundle_kernel(
    const float* __restrict__ w,
    const float* __restrict__ x,
    const float* __restrict__ v,
    const float* __restrict__ r,
    float* __restrict__ out_v,
    float* __restrict__ out_r,
    float* __restrict__ out_w)
{
    const int n = blockIdx.x;          // one block per neuron row
    const int t = threadIdx.x;

    const v4f* __restrict__ wrow = (const v4f*)(w + (size_t)n * ROW_FLOATS);
    const v4f* __restrict__ x4   = (const v4f*)x;
    v4f* __restrict__ owrow      = (v4f*)(out_w + (size_t)n * ROW_FLOATS);

    // --- load row into registers (nontemporal: w is stream-once, keep x in L2),
    //     accumulate per-k partial dot products ---
    v4f wv[VEC_PER_THR];
    v4f acc = (v4f){0.f, 0.f, 0.f, 0.f};
#pragma unroll
    for (int u = 0; u < VEC_PER_THR; ++u) {
        const int j = t + u * BLOCK_T;          // coalesced across the wave
        wv[u] = __builtin_nontemporal_load(&wrow[j]);
        v4f xv = x4[j];                          // x flat index == i*4+k layout (L2-hot)
        acc.x = fmaf(wv[u].x, xv.x, acc.x);
        acc.y = fmaf(wv[u].y, xv.y, acc.y);
        acc.z = fmaf(wv[u].z, xv.z, acc.z);
        acc.w = fmaf(wv[u].w, xv.w, acc.w);
    }

    // --- wave (64-lane) butterfly reduce ---
#pragma unroll
    for (int off = 32; off > 0; off >>= 1) {
        acc.x += __shfl_down(acc.x, off);
        acc.y += __shfl_down(acc.y, off);
        acc.z += __shfl_down(acc.z, off);
        acc.w += __shfl_down(acc.w, off);
    }

    // --- cross-wave reduce via LDS (8 waves) ---
    __shared__ v4f smem[N_WAVES];
    __shared__ v4f I_sh;
    __shared__ float g_sh;        // reg / TAU_W
    const int wave = t >> 6;
    const int lane = t & 63;
    if (lane == 0) smem[wave] = acc;
    __syncthreads();

    if (t == 0) {
        v4f I = smem[0];
#pragma unroll
        for (int i = 1; i < N_WAVES; ++i) I += smem[i];
        const float vn = v[n];
        const float dv = (I.x - I.y + I.z - I.w - vn) * DT_OVER_TAUV;
        const float th = tanhf(vn);              // ACT_ALPHA = 1, THRES = 0
        const float actd = (vn > 0.f) ? (1.f - th * th) : 0.f;
        const float reg  = r[n] * actd * dv;
        I_sh = I;
        g_sh = reg * INV_TAU_W;
        out_v[n] = vn + dv;
        out_r[n] = (vn > 0.f) ? th : 0.f;
    }
    __syncthreads();

    const v4f I = I_sh;
    const float g = g_sh;

    // --- update row from registers; re-read x (L2-hot, 128 KiB shared by all
    //     blocks); nontemporal store (w_new is never re-read) ---
#pragma unroll
    for (int u = 0; u < VEC_PER_THR; ++u) {
        const int j = t + u * BLOCK_T;
        v4f xv = x4[j];
        v4f o;
        o.x = fmaf(g, fmaf(xv.x, ALPHA, -wv[u].x * I.x), wv[u].x);
        o.y = fmaf(g, fmaf(xv.y, ALPHA, -wv[u].y * I.y), wv[u].y);
        o.z = fmaf(g, fmaf(xv.z, ALPHA, -wv[u].z * I.z), wv[u].z);
        o.w = fmaf(g, fmaf(xv.w, ALPHA, -wv[u].w * I.w), wv[u].w);
        __builtin_nontemporal_store(o, &owrow[j]);
    }
}

extern "C" void kernel_launch(void* const* d_in, const int* in_sizes, int n_in,
                              void* d_out, int out_size, void* d_ws, size_t ws_size,
                              hipStream_t stream) {
    const float* w = (const float*)d_in[0];   // [4096, 8192, 4]
    const float* x = (const float*)d_in[1];   // [8192, 4]
    const float* v = (const float*)d_in[2];   // [4096]
    const float* r = (const float*)d_in[3];   // [4096]

    float* out_v = (float*)d_out;                       // [4096]
    float* out_r = out_v + N_NEURONS;                   // [4096]
    float* out_w = out_r + N_NEURONS;                   // [4096, 8192, 4]

    dv_bundle_kernel<<<N_NEURONS, BLOCK_T, 0, stream>>>(w, x, v, r, out_v, out_r, out_w);
}